// Round 4
// baseline (486.437 us; speedup 1.0000x reference)
//
#include <hip/hip_runtime.h>

#define N_ATOMS   100000
#define N_BONDS   200000
#define MAX_NB    6
#define AF        39
#define BFEAT     50      // 39 + 11
#define H         128
#define DEPTH     6
#define KS_I      2       // k-steps (32 each): binput GEMM (K=64 padded)
#define KS_H      4       // k_mp GEMM over nei only (K=128); W_i part via acc-init
#define KS_O      6       // output GEMM (K=192 padded)
#define FAW       64      // padded bf16 fatoms row width
#define NTILES    (N_BONDS / 64)   // 3125
#define GMP       1024             // k_mp grid (pipelined, grid-stride)

typedef unsigned short ushort_t;
typedef unsigned int   uint_t;

typedef __attribute__((ext_vector_type(8))) short  bf16x8;
typedef __attribute__((ext_vector_type(4))) float  f32x4;

// hardware packed f32->bf16 (RNE)
__device__ inline uint_t cvt_pk(float lo, float hi) {
    uint_t r;
    asm("v_cvt_pk_bf16_f32 %0, %1, %2" : "=v"(r) : "v"(lo), "v"(hi));
    return r;
}
__device__ inline ushort_t f2bf(float f) { return (ushort_t)cvt_pk(f, f); }
__device__ inline float bflo(uint_t u) { union { uint_t i; float f; } v; v.i = u << 16; return v.f; }
__device__ inline float bfhi(uint_t u) { union { uint_t i; float f; } v; v.i = u & 0xffff0000u; return v.f; }

// unpack-accumulate 8 bf16 (no relu: messages stored POST-relu)
__device__ inline void addv(float* a, uint4 v) {
    a[0] += bflo(v.x); a[1] += bfhi(v.x);
    a[2] += bflo(v.y); a[3] += bfhi(v.y);
    a[4] += bflo(v.z); a[5] += bfhi(v.z);
    a[6] += bflo(v.w); a[7] += bfhi(v.w);
}

// raw barrier: LDS-visibility only; leaves vmem (gathers/stores) IN FLIGHT.
// __syncthreads would emit s_waitcnt vmcnt(0) and kill the pipeline.
__device__ inline void barx() {
    asm volatile("s_waitcnt lgkmcnt(0)" ::: "memory");
    __builtin_amdgcn_s_barrier();
    __builtin_amdgcn_sched_barrier(0);
}

// ---------------------------------------------------------------------------
// Pack weights to MFMA B-fragment-major bf16: p[ks][nt][lane][j],
//   n = nt*16 + (lane&15),  k = ks*32 + (lane>>4)*8 + j
// pWi: K=64 (cols 0..49 = W_i);  pWh: K=128 (= W_h);  pWo: K=192.
// ---------------------------------------------------------------------------
__global__ __launch_bounds__(256) void k_pack(const float* __restrict__ W_i,
                                              const float* __restrict__ W_h,
                                              const float* __restrict__ W_o,
                                              ushort_t* __restrict__ pWi,
                                              ushort_t* __restrict__ pWh,
                                              ushort_t* __restrict__ pWo) {
    int id = blockIdx.x * 256 + threadIdx.x;   // 6144 ids
    int mat;
    ushort_t* dst;
    if (id < 1024)      { mat = 0; dst = pWi; }
    else if (id < 3072) { mat = 1; dst = pWh; id -= 1024; }
    else                { mat = 2; dst = pWo; id -= 3072; }
    const int lane = id & 63;
    const int nt   = (id >> 6) & 7;
    const int ks   = id >> 9;
    const int n  = nt * 16 + (lane & 15);
    const int k0 = ks * 32 + (lane >> 4) * 8;
    float v[8];
#pragma unroll
    for (int j = 0; j < 8; ++j) {
        const int k = k0 + j;
        float x = 0.f;
        if (mat == 0)      { if (k < BFEAT) x = W_i[n * BFEAT + k]; }
        else if (mat == 1) { x = W_h[n * H + k]; }
        else {
            if (k < H)           x = W_o[(size_t)n * (AF + H) + AF + k];
            else if (k < H + AF) x = W_o[(size_t)n * (AF + H) + (k - H)];
        }
        v[j] = x;
    }
    uint4 u;
    u.x = cvt_pk(v[0], v[1]); u.y = cvt_pk(v[2], v[3]);
    u.z = cvt_pk(v[4], v[5]); u.w = cvt_pk(v[6], v[7]);
    ((uint4*)dst)[id] = u;
}

// ---------------------------------------------------------------------------
// Pad fatoms to bf16[N_ATOMS][64] (MFMA-fragment-readable) for k_out.
// ---------------------------------------------------------------------------
__global__ __launch_bounds__(256) void k_fab(const float* __restrict__ fatoms,
                                             ushort_t* __restrict__ fab) {
    const int t = threadIdx.x;
    const int a0 = blockIdx.x * 64;
    const int row = t >> 2;
    const int c0 = (t & 3) * 16;
    const int a = a0 + row;
    if (a >= N_ATOMS) return;
    float v[16];
#pragma unroll
    for (int j = 0; j < 16; ++j) {
        const int c = c0 + j;
        v[j] = (c < AF) ? fatoms[(size_t)a * AF + c] : 0.f;
    }
    uint4 u0, u1;
    u0.x = cvt_pk(v[0],  v[1]);  u0.y = cvt_pk(v[2],  v[3]);
    u0.z = cvt_pk(v[4],  v[5]);  u0.w = cvt_pk(v[6],  v[7]);
    u1.x = cvt_pk(v[8],  v[9]);  u1.y = cvt_pk(v[10], v[11]);
    u1.z = cvt_pk(v[12], v[13]); u1.w = cvt_pk(v[14], v[15]);
    *(uint4*)(fab + (size_t)a * FAW + c0)     = u0;
    *(uint4*)(fab + (size_t)a * FAW + c0 + 8) = u1;
}

// ---------------------------------------------------------------------------
// k_binput: msg0 = relu(fbonds @ W_i^T) (bf16, POST-relu, row layout) AND
// binputP = PRE-relu binput in C-fragment pair layout:
//   uint4 #i of (tile,wave,lane) at [((tile*4+w)*4+i)*64 + lane], i=0..3,
//   uint j (0..15) = cvt_pk(acc[j>>1][(j&1)*2], acc[j>>1][(j&1)*2+1]).
// k_mp initializes its MFMA accumulator from binputP (residual fusion).
// ---------------------------------------------------------------------------
__global__ __launch_bounds__(256) void k_binput(const float* __restrict__ fbonds,
                                                const ushort_t* __restrict__ pWi,
                                                ushort_t* __restrict__ bP,
                                                ushort_t* __restrict__ msg0) {
    __shared__ __align__(16) ushort_t sAC[64][136];
    const int t = threadIdx.x;
    const int b0 = blockIdx.x * 64;

    for (int i = t; i < 64 * 25; i += 256) {
        const int row = i / 25, j = i % 25;
        const float2 v = *(const float2*)(fbonds + (size_t)(b0 + row) * BFEAT + j * 2);
        *(uint_t*)&sAC[row][j * 2] = cvt_pk(v.x, v.y);
    }
    for (int i = t; i < 64 * 7; i += 256) {
        const int row = i / 7, c = BFEAT + (i % 7) * 2;
        *(uint_t*)&sAC[row][c] = 0u;
    }
    __syncthreads();

    const int w    = t >> 6;
    const int lane = t & 63;
    const int col  = lane & 15;
    const int kg   = lane >> 4;
    const int m    = 16 * w + col;

    f32x4 acc[8];
#pragma unroll
    for (int nt = 0; nt < 8; ++nt) acc[nt] = (f32x4){0.f, 0.f, 0.f, 0.f};
    bf16x8 af[KS_I];
#pragma unroll
    for (int ks = 0; ks < KS_I; ++ks)
        af[ks] = *(const bf16x8*)&sAC[m][ks * 32 + kg * 8];
#pragma unroll
    for (int ks = 0; ks < KS_I; ++ks) {
#pragma unroll
        for (int nt = 0; nt < 8; ++nt) {
            const bf16x8 b = *(const bf16x8*)(pWi + (((size_t)(ks * 8 + nt) * 64 + lane) * 8));
            acc[nt] = __builtin_amdgcn_mfma_f32_16x16x32_bf16(af[ks], b, acc[nt], 0, 0, 0);
        }
    }

    // binputP (pre-relu, fragment-pair layout, coalesced)
    {
        uint_t u[16];
#pragma unroll
        for (int nt = 0; nt < 8; ++nt) {
            u[nt * 2]     = cvt_pk(acc[nt][0], acc[nt][1]);
            u[nt * 2 + 1] = cvt_pk(acc[nt][2], acc[nt][3]);
        }
        uint4* base = (uint4*)bP + (size_t)(blockIdx.x * 4 + w) * 256 + lane;
#pragma unroll
        for (int i = 0; i < 4; ++i) {
            uint4 q;
            q.x = u[4 * i]; q.y = u[4 * i + 1]; q.z = u[4 * i + 2]; q.w = u[4 * i + 3];
            base[i * 64] = q;
        }
    }

    // msg0 = relu'd bf16, standard row layout (own-wave slab; af pre-loaded)
    const int row0 = kg * 4;
#pragma unroll
    for (int nt = 0; nt < 8; ++nt)
#pragma unroll
        for (int r = 0; r < 4; ++r)
            sAC[16 * w + row0 + r][nt * 16 + col] = f2bf(fmaxf(acc[nt][r], 0.f));
    __syncthreads();

    for (int i = t; i < 64 * 16; i += 256) {
        const int row = i >> 4, c0 = (i & 15) * 8;
        *(uint4*)(msg0 + (size_t)(b0 + row) * H + c0) = *(const uint4*)&sAC[row][c0];
    }
}

// ---------------------------------------------------------------------------
// k_mp (PIPELINED): grid-stride over tiles; gathers for tile t+1 issued
// before MFMA of tile t (hidden under MFMA + epilogue). W_h fragments staged
// in LDS (B reads = lgkm-counted, so vmcnt waits never drain the gathers).
// Residual via acc-init from binputP. C stored direct to global (post-relu).
// LDS: sA 17408 + sWh 32768 + sIdx 2x1536 = 53248.
// ---------------------------------------------------------------------------
__global__ __launch_bounds__(256) void k_mp(const ushort_t* __restrict__ msg_in,
                                            const int* __restrict__ bgraph,
                                            const ushort_t* __restrict__ pWh,
                                            const ushort_t* __restrict__ binputP,
                                            ushort_t* __restrict__ msg_out) {
    __shared__ __align__(16) ushort_t sA[64][136];           // gathered nei A-tile
    __shared__ __align__(16) ushort_t sWh[KS_H * 8 * 64 * 8]; // 32 KB W_h B-frags
    __shared__ __align__(16) int sIdx[2][64 * MAX_NB];       // double-buffered idx
    const int t = threadIdx.x;
    const int bi = t >> 4;
    const int c0 = (t & 15) * 8;
    const int w = t >> 6, lane = t & 63, col = lane & 15, kg = lane >> 4;
    const int m = 16 * w + col;
    const int G = GMP;

    int tile = blockIdx.x;

    // ---- prologue: stage W_h to LDS, idx(tile) to sIdx[0]
    {
        const uint4* src = (const uint4*)pWh;
        uint4* dst = (uint4*)sWh;
#pragma unroll
        for (int i = 0; i < 8; ++i) dst[t + i * 256] = src[t + i * 256];
    }
    if (t < 96)
        ((int4*)sIdx[0])[t] = ((const int4*)(bgraph + (size_t)tile * 384))[t];
    barx();

    uint4 g[24];
#pragma unroll
    for (int r = 0; r < 4; ++r)
#pragma unroll
        for (int j = 0; j < 6; ++j) {
            const uint_t off = (uint_t)sIdx[0][(r * 16 + bi) * 6 + j] * H + c0;
            g[r * 6 + j] = *(const uint4*)(msg_in + off);
        }
    int4 idxPF = {0, 0, 0, 0};
    if (t < 96 && tile + G < NTILES)
        idxPF = ((const int4*)(bgraph + (size_t)(tile + G) * 384))[t];

    int ib = 1;
    for (;;) {
        const int b0 = tile * 64;
        // binputP loads (older than next gathers -> waiting them is safe)
        const uint4* bp4 = (const uint4*)binputP + (size_t)(tile * 4 + w) * 256 + lane;
        uint4 q0 = bp4[0], q1 = bp4[64], q2 = bp4[128], q3 = bp4[192];

        // accumulate gathered rows -> bf16 A tile (consumes g, staggered waits)
#pragma unroll
        for (int r = 0; r < 4; ++r) {
            float a8[8];
#pragma unroll
            for (int qq = 0; qq < 8; ++qq) a8[qq] = 0.f;
#pragma unroll
            for (int j = 0; j < 6; ++j) addv(a8, g[r * 6 + j]);
            uint4 u;
            u.x = cvt_pk(a8[0], a8[1]); u.y = cvt_pk(a8[2], a8[3]);
            u.z = cvt_pk(a8[4], a8[5]); u.w = cvt_pk(a8[6], a8[7]);
            *(uint4*)&sA[r * 16 + bi][c0] = u;
        }

        const bool hasN = (tile + G) < NTILES;
        if (t < 96 && hasN) ((int4*)sIdx[ib])[t] = idxPF;
        if (t < 96 && (tile + 2 * G) < NTILES)
            idxPF = ((const int4*)(bgraph + (size_t)(tile + 2 * G) * 384))[t];

        barx();   // A(t) + idx(t+G) visible

        // issue gathers for t+G — stay in flight across MFMA (raw barriers,
        // vmem waits below only target older loads)
        if (hasN) {
#pragma unroll
            for (int r = 0; r < 4; ++r)
#pragma unroll
                for (int j = 0; j < 6; ++j) {
                    const uint_t off = (uint_t)sIdx[ib][(r * 16 + bi) * 6 + j] * H + c0;
                    g[r * 6 + j] = *(const uint4*)(msg_in + off);
                }
        }

        bf16x8 af[KS_H];
#pragma unroll
        for (int ks = 0; ks < KS_H; ++ks)
            af[ks] = *(const bf16x8*)&sA[m][ks * 32 + kg * 8];

        barx();   // all af reads done before next iteration's addv overwrites sA

        // acc init = pre-relu binput (residual); waits binputP only
        f32x4 acc[8];
#pragma unroll
        for (int i = 0; i < 4; ++i) {
            const uint4 q = (i == 0) ? q0 : (i == 1) ? q1 : (i == 2) ? q2 : q3;
            acc[2 * i][0]     = bflo(q.x); acc[2 * i][1]     = bfhi(q.x);
            acc[2 * i][2]     = bflo(q.y); acc[2 * i][3]     = bfhi(q.y);
            acc[2 * i + 1][0] = bflo(q.z); acc[2 * i + 1][1] = bfhi(q.z);
            acc[2 * i + 1][2] = bflo(q.w); acc[2 * i + 1][3] = bfhi(q.w);
        }
#pragma unroll
        for (int ks = 0; ks < KS_H; ++ks)
#pragma unroll
            for (int nt = 0; nt < 8; ++nt) {
                const bf16x8 b = *(const bf16x8*)&sWh[((ks * 8 + nt) * 64 + lane) * 8];
                acc[nt] = __builtin_amdgcn_mfma_f32_16x16x32_bf16(af[ks], b, acc[nt], 0, 0, 0);
            }

        // C: relu + direct bf16 stores (full 256B rows per wave -> L2 merges)
        const int rowb = b0 + 16 * w + kg * 4;
#pragma unroll
        for (int r = 0; r < 4; ++r) {
            ushort_t* op = msg_out + (size_t)(rowb + r) * H + col;
#pragma unroll
            for (int nt = 0; nt < 8; ++nt)
                op[nt * 16] = f2bf(fmaxf(acc[nt][r], 0.f));
        }

        tile += G;
        if (tile >= NTILES) break;
        ib ^= 1;
    }
}

// ---------------------------------------------------------------------------
// Fused output: out = relu(b_o + [gather(128) | fatoms_bf16(64)] @ W_o^T)
// (unchanged from R3)
// ---------------------------------------------------------------------------
__global__ __launch_bounds__(256) void k_out(const ushort_t* __restrict__ msg,
                                             const int* __restrict__ agraph,
                                             const ushort_t* __restrict__ fab,
                                             const ushort_t* __restrict__ pWo,
                                             const float* __restrict__ b_o,
                                             float* __restrict__ out) {
    __shared__ __align__(16) ushort_t sA[64][136];
    __shared__ int sIdx[64][MAX_NB];
    const int t = threadIdx.x;
    const int a0 = blockIdx.x * 64;

    for (int i = t; i < 64 * MAX_NB; i += 256) {
        const int a = a0 + i / MAX_NB;
        sIdx[i / MAX_NB][i % MAX_NB] = (a < N_ATOMS) ? agraph[(size_t)a * MAX_NB + (i % MAX_NB)] : 0;
    }
    __syncthreads();

    {
        const int bi = t >> 4;
        const int c0 = (t & 15) * 8;
#pragma unroll
        for (int p = 0; p < 4; p += 2) {
            const int iA = p * 16 + bi;
            const int iB = iA + 16;
            uint4 vA[MAX_NB], vB[MAX_NB];
#pragma unroll
            for (int j = 0; j < MAX_NB; ++j)
                vA[j] = *(const uint4*)(msg + (size_t)sIdx[iA][j] * H + c0);
#pragma unroll
            for (int j = 0; j < MAX_NB; ++j)
                vB[j] = *(const uint4*)(msg + (size_t)sIdx[iB][j] * H + c0);
            float a[8], b[8];
#pragma unroll
            for (int q = 0; q < 8; ++q) { a[q] = 0.f; b[q] = 0.f; }
#pragma unroll
            for (int j = 0; j < MAX_NB; ++j) addv(a, vA[j]);
#pragma unroll
            for (int j = 0; j < MAX_NB; ++j) addv(b, vB[j]);
            uint4 ua, ub;
            ua.x = cvt_pk(a[0], a[1]); ua.y = cvt_pk(a[2], a[3]);
            ua.z = cvt_pk(a[4], a[5]); ua.w = cvt_pk(a[6], a[7]);
            ub.x = cvt_pk(b[0], b[1]); ub.y = cvt_pk(b[2], b[3]);
            ub.z = cvt_pk(b[4], b[5]); ub.w = cvt_pk(b[6], b[7]);
            *(uint4*)&sA[iA][c0] = ua;
            *(uint4*)&sA[iB][c0] = ub;
        }
    }

    const int w    = t >> 6;
    const int lane = t & 63;
    const int col  = lane & 15;
    const int kg   = lane >> 4;
    const int m    = 16 * w + col;
    const int am   = a0 + m;
    const size_t amc = (size_t)((am < N_ATOMS) ? am : 0);

    bf16x8 af[KS_O];
    af[4] = *(const bf16x8*)(fab + amc * FAW + kg * 8);
    af[5] = *(const bf16x8*)(fab + amc * FAW + 32 + kg * 8);
    __syncthreads();
#pragma unroll
    for (int ks = 0; ks < 4; ++ks)
        af[ks] = *(const bf16x8*)&sA[m][ks * 32 + kg * 8];

    f32x4 acc[8];
#pragma unroll
    for (int nt = 0; nt < 8; ++nt) acc[nt] = (f32x4){0.f, 0.f, 0.f, 0.f};
#pragma unroll
    for (int ks = 0; ks < KS_O; ++ks) {
#pragma unroll
        for (int nt = 0; nt < 8; ++nt) {
            const bf16x8 b = *(const bf16x8*)(pWo + (((size_t)(ks * 8 + nt) * 64 + lane) * 8));
            acc[nt] = __builtin_amdgcn_mfma_f32_16x16x32_bf16(af[ks], b, acc[nt], 0, 0, 0);
        }
    }

    float bias[8];
#pragma unroll
    for (int nt = 0; nt < 8; ++nt) bias[nt] = b_o[nt * 16 + col];
    const int rowbase = a0 + 16 * w + kg * 4;
#pragma unroll
    for (int nt = 0; nt < 8; ++nt) {
#pragma unroll
        for (int r = 0; r < 4; ++r) {
            const int arow = rowbase + r;
            if (arow < N_ATOMS)
                out[(size_t)arow * H + nt * 16 + col] = fmaxf(acc[nt][r] + bias[nt], 0.f);
        }
    }
}

// ---------------------------------------------------------------------------
extern "C" void kernel_launch(void* const* d_in, const int* in_sizes, int n_in,
                              void* d_out, int out_size, void* d_ws, size_t ws_size,
                              hipStream_t stream) {
    const float* fatoms = (const float*)d_in[0];
    const float* fbonds = (const float*)d_in[1];
    const int*   agraph = (const int*)d_in[2];
    const int*   bgraph = (const int*)d_in[3];
    const float* W_i    = (const float*)d_in[4];
    const float* W_h    = (const float*)d_in[5];
    const float* W_o    = (const float*)d_in[6];
    const float* b_o    = (const float*)d_in[7];
    float* out = (float*)d_out;

    const size_t MSG_BYTES = (size_t)N_BONDS * H * sizeof(ushort_t);     // 51.2 MB
    const size_t FAB_BYTES = (size_t)N_ATOMS * FAW * sizeof(ushort_t);   // 12.8 MB
    char* ws = (char*)d_ws;
    ushort_t* m0   = (ushort_t*)(ws);
    ushort_t* m1   = (ushort_t*)(ws + MSG_BYTES);
    ushort_t* bP   = (ushort_t*)(ws + 2 * MSG_BYTES);                    // 51.2 MB
    ushort_t* fab  = (ushort_t*)(ws + 3 * MSG_BYTES);
    char*     wb   = ws + 3 * MSG_BYTES + FAB_BYTES;
    ushort_t* pWi  = (ushort_t*)(wb);              // 16 KB
    ushort_t* pWh  = (ushort_t*)(wb + 16 * 1024);  // 32 KB
    ushort_t* pWo  = (ushort_t*)(wb + 48 * 1024);  // 48 KB

    k_pack<<<24, 256, 0, stream>>>(W_i, W_h, W_o, pWi, pWh, pWo);
    k_fab<<<(N_ATOMS + 63) / 64, 256, 0, stream>>>(fatoms, fab);
    k_binput<<<N_BONDS / 64, 256, 0, stream>>>(fbonds, pWi, bP, m0);

    ushort_t* cur = m0;
    ushort_t* nxt = m1;
    for (int d = 0; d < DEPTH - 1; ++d) {
        k_mp<<<GMP, 256, 0, stream>>>(cur, bgraph, pWh, bP, nxt);
        ushort_t* tmp = cur; cur = nxt; nxt = tmp;
    }

    k_out<<<(N_ATOMS + 63) / 64, 256, 0, stream>>>(cur, agraph, fab, pWo, b_o, out);
}